// Round 22
// baseline (278.875 us; speedup 1.0000x reference)
//
#include <hip/hip_runtime.h>

#define BS 256

// ---------------- bf16 helpers ----------------
__device__ __forceinline__ unsigned short f2bf(float f) {
    unsigned x = __float_as_uint(f);
    return (unsigned short)((x + 0x7fffu + ((x >> 16) & 1u)) >> 16);
}
__device__ __forceinline__ unsigned pack2bf(float a, float b) {
    return (unsigned)f2bf(a) | ((unsigned)f2bf(b) << 16);
}
__device__ __forceinline__ void unpack2(unsigned u, float* d) {
    d[0] = __uint_as_float(u << 16);
    d[1] = __uint_as_float(u & 0xFFFF0000u);
}
__device__ __forceinline__ void unpack8(uint4 v, float* d) {
    unpack2(v.x, d); unpack2(v.y, d + 2); unpack2(v.z, d + 4); unpack2(v.w, d + 6);
}
__device__ __forceinline__ uint4 pack8bf(const float* r) {
    return make_uint4(pack2bf(r[0], r[1]), pack2bf(r[2], r[3]),
                      pack2bf(r[4], r[5]), pack2bf(r[6], r[7]));
}

// ---- fused: histogram + edge trunk (edge-order, no offs dep) + node prep ----
// blocks [0, nbDeg2): one-atomic-per-thread histogram (2E threads)
// blocks [nbDeg2, nbDeg2+nbEdges): edge trunk -> er_e[e][16] bf16, coalesced
// blocks [nbDeg2+nbEdges, +nbPrep): node prep
__global__ __launch_bounds__(BS) void prep_deg_er_kernel(
    const float* __restrict__ xf,
    const float* __restrict__ W1, const float* __restrict__ b1,
    const float* __restrict__ W2, const float* __restrict__ b2,
    float* __restrict__ x16,
    const int* __restrict__ srcA, const int* __restrict__ dstA,
    int* __restrict__ cntS, int* __restrict__ cntD,
    int* __restrict__ jS, int* __restrict__ jD,
    const float* __restrict__ eattr,
    const float* __restrict__ eW1, const float* __restrict__ eb1,
    const float* __restrict__ eW2, const float* __restrict__ eb2,
    unsigned short* __restrict__ er_e,
    int N, int E, int nbDeg2, int nbEdges)
{
    int bx = blockIdx.x;
    if (bx < nbDeg2) {
        int tid = bx * BS + threadIdx.x;
        if (tid < E) {
            jS[tid] = atomicAdd(&cntS[srcA[tid]], 1);
        } else if (tid < 2 * E) {
            int e = tid - E;
            jD[e] = atomicAdd(&cntD[dstA[e]], 1);
        }
    } else if (bx < nbDeg2 + nbEdges) {
        // ---- edge trunk, edge order, coalesced output ----
        int e = (bx - nbDeg2) * BS + threadIdx.x;
        if (e >= E) return;
        float ea[16];
#pragma unroll
        for (int i = 0; i < 16; i += 4)
            *(float4*)(ea + i) = *(const float4*)(eattr + (size_t)e * 16 + i);
        float h[32];
#pragma unroll
        for (int j = 0; j < 32; j++) {
            float t = eb1[j];
#pragma unroll
            for (int i = 0; i < 16; i++) t = fmaf(ea[i], eW1[i * 32 + j], t);
            h[j] = fmaxf(t, 0.f);
        }
        float er[16];
#pragma unroll
        for (int j = 0; j < 16; j++) {
            float t = eb2[j];
#pragma unroll
            for (int i = 0; i < 32; i++) t = fmaf(h[i], eW2[i * 16 + j], t);
            er[j] = 1.f / (1.f + __expf(-t));
        }
        uint4* qo = (uint4*)(er_e + (size_t)e * 16);
        qo[0] = pack8bf(er);
        qo[1] = pack8bf(er + 8);
    } else {
        // ---- node prep ----
        int n = (bx - nbDeg2 - nbEdges) * BS + threadIdx.x;
        bool valid = n < N;
        int nn = valid ? n : 0;
        float a[24];
#pragma unroll
        for (int i = 0; i < 24; i += 4)
            *(float4*)(a + i) = *(const float4*)(xf + (size_t)nn * 24 + i);
        float h[32];
#pragma unroll
        for (int j = 0; j < 32; j++) {
            float s = b1[j];
#pragma unroll
            for (int i = 0; i < 24; i++) s = fmaf(a[i], W1[i * 32 + j], s);
            h[j] = fmaxf(s, 0.f);
        }
        if (!valid) return;
#pragma unroll
        for (int j = 0; j < 16; j++) {
            float s = b2[j];
#pragma unroll
            for (int i = 0; i < 32; i++) s = fmaf(h[i], W2[i * 16 + j], s);
            x16[(size_t)n * 16 + j] = fmaxf(s, 0.f);
        }
    }
}

// ---- fused: wave-scan offsets (blocks < nbOff) + ynode<16> (rest) ----
__global__ __launch_bounds__(BS) void offs_ynode16_kernel(
    const int* __restrict__ cntS, const int* __restrict__ cntD,
    int* __restrict__ offsS, int* __restrict__ offsD,
    int* __restrict__ cursS, int* __restrict__ cursD,
    const float* __restrict__ x,
    const float* __restrict__ W,   // [3][16][16*8]
    const float* __restrict__ B,   // [3][16*8]
    const float* __restrict__ RW,  // [3][16][8]
    const float* __restrict__ RB,  // [3][8]
    unsigned short* __restrict__ Y,
    float* __restrict__ root,
    int N, int nbOff, int nbY3)
{
    if ((int)blockIdx.x < nbOff) {
        int n = blockIdx.x * BS + threadIdx.x;
        int lane = threadIdx.x & 63;
        bool valid = n < N;
        int dS = valid ? cntS[n] : 0;
        int dD = valid ? cntD[n] : 0;
        int sS = dS, sD = dD;
#pragma unroll
        for (int o = 1; o < 64; o <<= 1) {
            int tS = __shfl_up(sS, o);
            int tD = __shfl_up(sD, o);
            if (lane >= o) { sS += tS; sD += tD; }
        }
        int totS = __shfl(sS, 63);
        int totD = __shfl(sD, 63);
        int baseS = 0, baseD = 0;
        if (lane == 63) {
            baseS = atomicAdd(cursS, totS);
            baseD = atomicAdd(cursD, totD);
        }
        baseS = __shfl(baseS, 63);
        baseD = __shfl(baseD, 63);
        if (valid) {
            offsS[n] = baseS + sS - dS;
            offsD[n] = baseD + sD - dD;
        }
    } else {
        // ---------------- ynode16 ----------------
        const int IN = 16;
        __shared__ float w_lds[16 * 24];
        int t = threadIdx.x;
        int blk = blockIdx.x - nbOff;
        int kb = blk / nbY3;
        int xb = blk - kb * nbY3;

        for (int idx = t; idx < IN * 24; idx += BS) {
            int i = idx / 24;
            int j = idx - i * 24;
            int a = j >> 3, o = j & 7;
            float v;
            if (kb < 16)       v = W[(((size_t)a * 16 + kb) * IN + i) * 8 + o];
            else if (kb == 16) v = B[((size_t)a * IN + i) * 8 + o];
            else               v = RW[((size_t)a * IN + i) * 8 + o];
            w_lds[idx] = v;
        }
        __syncthreads();

        int tid = xb * BS + t;
        int n = tid / 3;
        int a = tid - n * 3;
        if (n >= N) return;

        float xv[IN];
#pragma unroll
        for (int i = 0; i < IN; i += 4)
            *(float4*)(xv + i) = *(const float4*)(x + (size_t)n * IN + i);

        float acc[8];
#pragma unroll
        for (int o = 0; o < 8; o++) acc[o] = 0.f;
        const float* wb = w_lds + a * 8;
#pragma unroll
        for (int i = 0; i < IN; i++) {
            float xi = xv[i];
#pragma unroll
            for (int o = 0; o < 8; o++)
                acc[o] = fmaf(xi, wb[i * 24 + o], acc[o]);
        }

        if (kb < 17) {
            *(uint4*)(Y + ((size_t)kb * N + n) * 24 + a * 8) = pack8bf(acc);
        } else {
            float* pr = root + (size_t)n * 24 + a * 8;
            *(float4*)(pr)     = make_float4(acc[0] + RB[a*8+0], acc[1] + RB[a*8+1],
                                             acc[2] + RB[a*8+2], acc[3] + RB[a*8+3]);
            *(float4*)(pr + 4) = make_float4(acc[4] + RB[a*8+4], acc[5] + RB[a*8+5],
                                             acc[6] + RB[a*8+6], acc[7] + RB[a*8+7]);
        }
    }
}

// ---- thin fill: read er_e coalesced, compute p/q, write 64B record scattered ----
__global__ __launch_bounds__(BS) void fill_kernel(
    const int* __restrict__ srcA, const int* __restrict__ dstA,
    const int* __restrict__ jS, const int* __restrict__ jD,
    const int* __restrict__ offsS, const int* __restrict__ offsD,
    const unsigned short* __restrict__ er_e,   // [E][16] bf16, edge order
    uint4* __restrict__ erec, int E)
{
    int e = blockIdx.x * BS + threadIdx.x;
    if (e >= E) return;
    int s = srcA[e], d = dstA[e];
    int p = offsS[s] + jS[e];
    int q = offsD[d] + jD[e];
    const uint4* ei = (const uint4*)(er_e + (size_t)e * 16);
    uint4 e0 = ei[0];
    uint4 e1 = ei[1];
    uint4* rp = erec + (size_t)p * 4;
    rp[0] = make_uint4((unsigned)s, (unsigned)q, e0.x, e0.y);
    rp[1] = make_uint4(e0.z, e0.w, e1.x, e1.y);
    rp[2] = make_uint4(e1.z, e1.w, 0u, 0u);
    rp[3] = make_uint4(0u, 0u, 0u, 0u);   // complete the 64B line
}

// ---- per-(node, 8-col chunk, k-slot) Y precompute (conv2) ----
template <int IN>
__global__ __launch_bounds__(BS) void ynode_kernel(const float* __restrict__ x,
                                                   const float* __restrict__ W,   // [3][16][IN*8]
                                                   const float* __restrict__ B,   // [3][IN*8]
                                                   const float* __restrict__ RW,  // [3][IN][8]
                                                   const float* __restrict__ RB,  // [3][8]
                                                   unsigned short* __restrict__ Y,
                                                   float* __restrict__ root, int N)
{
    __shared__ float w_lds[IN * 24];
    int t = threadIdx.x;
    int k = blockIdx.y;            // 0..17, block-uniform

    for (int idx = t; idx < IN * 24; idx += BS) {
        int i = idx / 24;
        int j = idx - i * 24;
        int a = j >> 3, o = j & 7;
        float v;
        if (k < 16)       v = W[(((size_t)a * 16 + k) * IN + i) * 8 + o];
        else if (k == 16) v = B[((size_t)a * IN + i) * 8 + o];
        else              v = RW[((size_t)a * IN + i) * 8 + o];
        w_lds[idx] = v;
    }
    __syncthreads();

    int tid = blockIdx.x * BS + t;
    int n = tid / 3;
    int a = tid - n * 3;
    if (n >= N) return;

    float xv[IN];
#pragma unroll
    for (int i = 0; i < IN; i += 4)
        *(float4*)(xv + i) = *(const float4*)(x + (size_t)n * IN + i);

    float acc[8];
#pragma unroll
    for (int o = 0; o < 8; o++) acc[o] = 0.f;
    const float* wb = w_lds + a * 8;
#pragma unroll
    for (int i = 0; i < IN; i++) {
        float xi = xv[i];
#pragma unroll
        for (int o = 0; o < 8; o++)
            acc[o] = fmaf(xi, wb[i * 24 + o], acc[o]);
    }

    if (k < 17) {
        *(uint4*)(Y + ((size_t)k * N + n) * 24 + a * 8) = pack8bf(acc);
    } else {
        float* pr = root + (size_t)n * 24 + a * 8;
        *(float4*)(pr)     = make_float4(acc[0] + RB[a*8+0], acc[1] + RB[a*8+1],
                                         acc[2] + RB[a*8+2], acc[3] + RB[a*8+3]);
        *(float4*)(pr + 4) = make_float4(acc[4] + RB[a*8+4], acc[5] + RB[a*8+5],
                                         acc[6] + RB[a*8+6], acc[7] + RB[a*8+7]);
    }
}

// ---- per-(edge, 8-col part) msg: one 64B record read, k-major 48B-row Y reads ----
__global__ __launch_bounds__(BS) void msg_kernel(
    const uint4* __restrict__ erec,            // [E][4] uint4
    const unsigned short* __restrict__ Y,      // [17][N][24] bf16
    unsigned short* __restrict__ msg16,        // [E][32] bf16, dst-sorted
    int N, int E)
{
    int tid = blockIdx.x * BS + threadIdx.x;
    int p = tid / 3;
    int j = tid - p * 3;
    if (p >= E) return;

    const uint4* rp = erec + (size_t)p * 4;
    uint4 r0 = rp[0];
    uint4 r1 = rp[1];
    uint4 r2 = rp[2];
    unsigned s = r0.x, q = r0.y;

    float er[16];
    unpack2(r0.z, er); unpack2(r0.w, er + 2);
    unpack8(r1, er + 4);
    unpack2(r2.x, er + 12); unpack2(r2.y, er + 14);

    const unsigned short* yb = Y + (size_t)s * 24 + j * 8;
    size_t kstride = (size_t)N * 24;

    float acc[8];
    unpack8(*(const uint4*)(yb + 16 * kstride), acc);   // bias slot
#pragma unroll
    for (int k = 0; k < 16; k++) {
        float t[8];
        unpack8(*(const uint4*)(yb + (size_t)k * kstride), t);
        float ek = er[k];
#pragma unroll
        for (int o = 0; o < 8; o++) acc[o] = fmaf(ek, t[o], acc[o]);
    }
    unsigned short* mrow = msg16 + (size_t)q * 32;
    *(uint4*)(mrow + j * 8) = pack8bf(acc);
    if (j == 0) *(uint4*)(mrow + 24) = make_uint4(0, 0, 0, 0);  // fill line
}

// ---- wave-per-node gather; FUSE_HEAD folds the output head in (conv2) ----
template <bool FUSE_HEAD>
__global__ __launch_bounds__(BS) void gather_kernel(
    const unsigned short* __restrict__ msg16,  // [E][32] bf16, dst-sorted
    const int* __restrict__ offs,
    const int* __restrict__ degi,
    const float* __restrict__ root,            // [N][24] fp32
    float* __restrict__ out,                   // x24 (conv1) or d_out (conv2)
    const float* __restrict__ oW, const float* __restrict__ ob,
    int N)
{
    int n = (blockIdx.x * BS + threadIdx.x) >> 6;   // one wave per node
    if (n >= N) return;
    int lane = threadIdx.x & 63;
    int c = lane & 3;     // uint4-chunk 0..3 (0..2 active)
    int r = lane >> 2;    // row within 16-row tile

    int off = offs[n];
    int d = degi[n];

    float s[8], m[8];
#pragma unroll
    for (int o = 0; o < 8; o++) { s[o] = 0.f; m[o] = -3.402823466e38f; }

    if (c < 3) {
        const unsigned short* base = msg16 + (size_t)off * 32 + c * 8;
        for (int j = r; j < d; j += 16) {
            uint4 v = *(const uint4*)(base + (size_t)j * 32);
            float t[8];
            unpack8(v, t);
#pragma unroll
            for (int o = 0; o < 8; o++) {
                s[o] += t[o];
                m[o] = fmaxf(m[o], t[o]);
            }
        }
    }
#pragma unroll
    for (int mask = 4; mask < 64; mask <<= 1) {
#pragma unroll
        for (int o = 0; o < 8; o++) {
            s[o] += __shfl_xor(s[o], mask);
            m[o] = fmaxf(m[o], __shfl_xor(m[o], mask));
        }
    }

    bool active = (lane < 3);
    float rr[8];
    if (active) {
        float inv = 1.f / fmaxf((float)d, 1.f);
        const float* pr = root + (size_t)n * 24 + lane * 8;
        float4 r0 = *(const float4*)(pr);
        float4 r1 = *(const float4*)(pr + 4);
        float rb[8] = {r0.x, r0.y, r0.z, r0.w, r1.x, r1.y, r1.z, r1.w};
#pragma unroll
        for (int o = 0; o < 8; o++) {
            float agg = (lane == 0) ? s[o] * inv
                      : (lane == 1) ? ((d > 0) ? m[o] : 0.f)
                      : s[o];
            rr[o] = fmaxf(rb[o] + agg, 0.f);
        }
    }

    if (!FUSE_HEAD) {
        if (active) {
            float* po = out + (size_t)n * 24 + lane * 8;
            *(float4*)(po)     = make_float4(rr[0], rr[1], rr[2], rr[3]);
            *(float4*)(po + 4) = make_float4(rr[4], rr[5], rr[6], rr[7]);
        }
    } else {
        float l0p = 0.f, l1p = 0.f;
        if (active) {
#pragma unroll
            for (int o = 0; o < 8; o++) {
                l0p = fmaf(rr[o], oW[(lane * 8 + o) * 2 + 0], l0p);
                l1p = fmaf(rr[o], oW[(lane * 8 + o) * 2 + 1], l1p);
            }
        }
        float l0 = __shfl(l0p, 0) + __shfl(l0p, 1) + __shfl(l0p, 2);
        float l1 = __shfl(l1p, 0) + __shfl(l1p, 1) + __shfl(l1p, 2);
        if (lane == 0) {
            l0 += ob[0]; l1 += ob[1];
            out[2 * (size_t)n + 0] = l0;
            out[2 * (size_t)n + 1] = l1;
            float mx = fmaxf(l0, l1);
            float e0 = __expf(l0 - mx), e1 = __expf(l1 - mx);
            float sm = e0 + e1;
            out[2 * (size_t)N + 2 * (size_t)n + 0] = e0 / sm;
            out[2 * (size_t)N + 2 * (size_t)n + 1] = e1 / sm;
        }
    }
}

extern "C" void kernel_launch(void* const* d_in, const int* in_sizes, int n_in,
                              void* d_out, int out_size, void* d_ws, size_t ws_size,
                              hipStream_t stream)
{
    const float* x_feat = (const float*)d_in[0];
    const int*   eidx   = (const int*)d_in[1];
    const float* eattr  = (const float*)d_in[2];
    const float* lpW = (const float*)d_in[3];
    const float* lpb = (const float*)d_in[4];
    const float* tW  = (const float*)d_in[5];
    const float* tb  = (const float*)d_in[6];
    const float* eW1 = (const float*)d_in[7];
    const float* eb1 = (const float*)d_in[8];
    const float* eW2 = (const float*)d_in[9];
    const float* eb2 = (const float*)d_in[10];
    const float* c1W = (const float*)d_in[11];
    const float* c1B = (const float*)d_in[12];
    const float* c1R = (const float*)d_in[13];
    const float* c1b = (const float*)d_in[14];
    const float* c2W = (const float*)d_in[15];
    const float* c2B = (const float*)d_in[16];
    const float* c2R = (const float*)d_in[17];
    const float* c2b = (const float*)d_in[18];
    const float* oW  = (const float*)d_in[19];
    const float* ob  = (const float*)d_in[20];

    int N = in_sizes[0] / 24;
    int E = in_sizes[1] / 2;
    const int* srcA = eidx;
    const int* dstA = eidx + E;

    char* wsb = (char*)d_ws;
    size_t off = 0;
    auto alloc = [&](size_t bytes) {
        off = (off + 255) & ~(size_t)255;
        void* p = wsb + off;
        off += bytes;
        return p;
    };
    unsigned short* Y     = (unsigned short*)alloc((size_t)17 * N * 24 * 2);
    unsigned short* msg16 = (unsigned short*)alloc((size_t)E * 32 * 2);
    uint4* erec = (uint4*)alloc((size_t)E * 64);
    unsigned short* er_e  = (unsigned short*)alloc((size_t)E * 16 * 2);
    float* root = (float*)alloc((size_t)N * 24 * 4);
    float* x16  = (float*)alloc((size_t)N * 16 * 4);
    float* x24a = (float*)alloc((size_t)N * 24 * 4);
    int* ibase  = (int*)alloc(((size_t)2 * N + 2) * 4);  // cntS | cntD | cursS | cursD (zeroed)
    int* cntS = ibase;
    int* cntD = ibase + N;
    int* cursS = ibase + 2 * N;
    int* cursD = ibase + 2 * N + 1;
    int* offsS = (int*)alloc((size_t)N * 4);
    int* offsD = (int*)alloc((size_t)N * 4);
    int* jS    = (int*)alloc((size_t)E * 4);
    int* jD    = (int*)alloc((size_t)E * 4);

    dim3 blk(BS);
    int nb_nodes = (N + BS - 1) / BS;
    int nb_deg2  = (2 * E + BS - 1) / BS;
    int nb_edges = (E + BS - 1) / BS;
    int nb_msg   = (3 * E + BS - 1) / BS;
    int nb_gath  = ((size_t)N * 64 + BS - 1) / BS;     // one wave per node
    int nb_y3    = (3 * N + BS - 1) / BS;              // thread = (node, chunk)
    int nbY      = nb_y3 * 18;                         // ynode16 flattened block count
    dim3 ygrid(nb_y3, 18);

    hipMemsetAsync(ibase, 0, (2 * (size_t)N + 2) * 4, stream);

    // fused histogram + edge trunk + node prep (all independent)
    prep_deg_er_kernel<<<nb_deg2 + nb_edges + nb_nodes, blk, 0, stream>>>(
        x_feat, lpW, lpb, tW, tb, x16, srcA, dstA, cntS, cntD, jS, jD,
        eattr, eW1, eb1, eW2, eb2, er_e, N, E, nb_deg2, nb_edges);

    // fused offsets (tiny) + ynode16 (depends only on x16)
    offs_ynode16_kernel<<<nb_nodes + nbY, blk, 0, stream>>>(
        cntS, cntD, offsS, offsD, cursS, cursD,
        x16, c1W, c1B, c1R, c1b, Y, root, N, nb_nodes, nb_y3);

    // thin fill: scatter er_e into src-sorted 64B records
    fill_kernel<<<nb_edges, blk, 0, stream>>>(srcA, dstA, jS, jD, offsS, offsD,
                                              er_e, erec, E);

    // ---- conv1 ----
    msg_kernel<<<nb_msg, blk, 0, stream>>>(erec, Y, msg16, N, E);
    gather_kernel<false><<<nb_gath, blk, 0, stream>>>(msg16, offsD, cntD, root, x24a,
                                                      oW, ob, N);

    // ---- conv2 (head fused into gather) ----
    ynode_kernel<24><<<ygrid, blk, 0, stream>>>(x24a, c2W, c2B, c2R, c2b, Y, root, N);
    msg_kernel<<<nb_msg, blk, 0, stream>>>(erec, Y, msg16, N, E);
    gather_kernel<true><<<nb_gath, blk, 0, stream>>>(msg16, offsD, cntD, root,
                                                     (float*)d_out, oW, ob, N);
}

// Round 23
// 260.363 us; speedup vs baseline: 1.0711x; 1.0711x over previous
//
#include <hip/hip_runtime.h>

#define BS 256

// ---------------- bf16 helpers ----------------
__device__ __forceinline__ unsigned short f2bf(float f) {
    unsigned x = __float_as_uint(f);
    return (unsigned short)((x + 0x7fffu + ((x >> 16) & 1u)) >> 16);
}
__device__ __forceinline__ unsigned pack2bf(float a, float b) {
    return (unsigned)f2bf(a) | ((unsigned)f2bf(b) << 16);
}
__device__ __forceinline__ void unpack2(unsigned u, float* d) {
    d[0] = __uint_as_float(u << 16);
    d[1] = __uint_as_float(u & 0xFFFF0000u);
}
__device__ __forceinline__ void unpack8(uint4 v, float* d) {
    unpack2(v.x, d); unpack2(v.y, d + 2); unpack2(v.z, d + 4); unpack2(v.w, d + 6);
}
__device__ __forceinline__ uint4 pack8bf(const float* r) {
    return make_uint4(pack2bf(r[0], r[1]), pack2bf(r[2], r[3]),
                      pack2bf(r[4], r[5]), pack2bf(r[6], r[7]));
}

// ---- fused per-thread: node prep (first nbPrep blocks) | edge combo (rest) ----
// Edge combo: load eattr, ISSUE both histogram atomics, compute trunk while
// they're in flight, then store jS/jD/er_e (all edge-order, coalesced).
__global__ __launch_bounds__(BS) void prep_combo_kernel(
    const float* __restrict__ xf,
    const float* __restrict__ W1, const float* __restrict__ b1,
    const float* __restrict__ W2, const float* __restrict__ b2,
    float* __restrict__ x16,
    const int* __restrict__ srcA, const int* __restrict__ dstA,
    int* __restrict__ cntS, int* __restrict__ cntD,
    int* __restrict__ jS, int* __restrict__ jD,
    const float* __restrict__ eattr,
    const float* __restrict__ eW1, const float* __restrict__ eb1,
    const float* __restrict__ eW2, const float* __restrict__ eb2,
    unsigned short* __restrict__ er_e,
    int N, int E, int nbPrep)
{
    int bx = blockIdx.x;
    if (bx < nbPrep) {
        // ---- node prep ----
        int n = bx * BS + threadIdx.x;
        bool valid = n < N;
        int nn = valid ? n : 0;
        float a[24];
#pragma unroll
        for (int i = 0; i < 24; i += 4)
            *(float4*)(a + i) = *(const float4*)(xf + (size_t)nn * 24 + i);
        float h[32];
#pragma unroll
        for (int j = 0; j < 32; j++) {
            float s = b1[j];
#pragma unroll
            for (int i = 0; i < 24; i++) s = fmaf(a[i], W1[i * 32 + j], s);
            h[j] = fmaxf(s, 0.f);
        }
        if (!valid) return;
#pragma unroll
        for (int j = 0; j < 16; j++) {
            float s = b2[j];
#pragma unroll
            for (int i = 0; i < 32; i++) s = fmaf(h[i], W2[i * 16 + j], s);
            x16[(size_t)n * 16 + j] = fmaxf(s, 0.f);
        }
    } else {
        // ---- edge combo: trunk FMAs hide the atomic round trip ----
        int e = (bx - nbPrep) * BS + threadIdx.x;
        if (e >= E) return;
        int s = srcA[e], d = dstA[e];

        float ea[16];                       // issue loads first (oldest vmcnt)
#pragma unroll
        for (int i = 0; i < 16; i += 4)
            *(float4*)(ea + i) = *(const float4*)(eattr + (size_t)e * 16 + i);

        int jsv = atomicAdd(&cntS[s], 1);   // in flight during trunk
        int jdv = atomicAdd(&cntD[d], 1);

        float h[32];
#pragma unroll
        for (int j = 0; j < 32; j++) {
            float t = eb1[j];
#pragma unroll
            for (int i = 0; i < 16; i++) t = fmaf(ea[i], eW1[i * 32 + j], t);
            h[j] = fmaxf(t, 0.f);
        }
        float er[16];
#pragma unroll
        for (int j = 0; j < 16; j++) {
            float t = eb2[j];
#pragma unroll
            for (int i = 0; i < 32; i++) t = fmaf(h[i], eW2[i * 16 + j], t);
            er[j] = 1.f / (1.f + __expf(-t));
        }
        uint4* qo = (uint4*)(er_e + (size_t)e * 16);
        qo[0] = pack8bf(er);
        qo[1] = pack8bf(er + 8);
        jS[e] = jsv;                        // waits vmcnt for atomics only here
        jD[e] = jdv;
    }
}

// ---- fused: wave-scan offsets (blocks < nbOff) + ynode<16> (rest) ----
__global__ __launch_bounds__(BS) void offs_ynode16_kernel(
    const int* __restrict__ cntS, const int* __restrict__ cntD,
    int* __restrict__ offsS, int* __restrict__ offsD,
    int* __restrict__ cursS, int* __restrict__ cursD,
    const float* __restrict__ x,
    const float* __restrict__ W,   // [3][16][16*8]
    const float* __restrict__ B,   // [3][16*8]
    const float* __restrict__ RW,  // [3][16][8]
    const float* __restrict__ RB,  // [3][8]
    unsigned short* __restrict__ Y,
    float* __restrict__ root,
    int N, int nbOff, int nbY3)
{
    if ((int)blockIdx.x < nbOff) {
        int n = blockIdx.x * BS + threadIdx.x;
        int lane = threadIdx.x & 63;
        bool valid = n < N;
        int dS = valid ? cntS[n] : 0;
        int dD = valid ? cntD[n] : 0;
        int sS = dS, sD = dD;
#pragma unroll
        for (int o = 1; o < 64; o <<= 1) {
            int tS = __shfl_up(sS, o);
            int tD = __shfl_up(sD, o);
            if (lane >= o) { sS += tS; sD += tD; }
        }
        int totS = __shfl(sS, 63);
        int totD = __shfl(sD, 63);
        int baseS = 0, baseD = 0;
        if (lane == 63) {
            baseS = atomicAdd(cursS, totS);
            baseD = atomicAdd(cursD, totD);
        }
        baseS = __shfl(baseS, 63);
        baseD = __shfl(baseD, 63);
        if (valid) {
            offsS[n] = baseS + sS - dS;
            offsD[n] = baseD + sD - dD;
        }
    } else {
        // ---------------- ynode16 ----------------
        const int IN = 16;
        __shared__ float w_lds[16 * 24];
        int t = threadIdx.x;
        int blk = blockIdx.x - nbOff;
        int kb = blk / nbY3;
        int xb = blk - kb * nbY3;

        for (int idx = t; idx < IN * 24; idx += BS) {
            int i = idx / 24;
            int j = idx - i * 24;
            int a = j >> 3, o = j & 7;
            float v;
            if (kb < 16)       v = W[(((size_t)a * 16 + kb) * IN + i) * 8 + o];
            else if (kb == 16) v = B[((size_t)a * IN + i) * 8 + o];
            else               v = RW[((size_t)a * IN + i) * 8 + o];
            w_lds[idx] = v;
        }
        __syncthreads();

        int tid = xb * BS + t;
        int n = tid / 3;
        int a = tid - n * 3;
        if (n >= N) return;

        float xv[IN];
#pragma unroll
        for (int i = 0; i < IN; i += 4)
            *(float4*)(xv + i) = *(const float4*)(x + (size_t)n * IN + i);

        float acc[8];
#pragma unroll
        for (int o = 0; o < 8; o++) acc[o] = 0.f;
        const float* wb = w_lds + a * 8;
#pragma unroll
        for (int i = 0; i < IN; i++) {
            float xi = xv[i];
#pragma unroll
            for (int o = 0; o < 8; o++)
                acc[o] = fmaf(xi, wb[i * 24 + o], acc[o]);
        }

        if (kb < 17) {
            *(uint4*)(Y + ((size_t)kb * N + n) * 24 + a * 8) = pack8bf(acc);
        } else {
            float* pr = root + (size_t)n * 24 + a * 8;
            *(float4*)(pr)     = make_float4(acc[0] + RB[a*8+0], acc[1] + RB[a*8+1],
                                             acc[2] + RB[a*8+2], acc[3] + RB[a*8+3]);
            *(float4*)(pr + 4) = make_float4(acc[4] + RB[a*8+4], acc[5] + RB[a*8+5],
                                             acc[6] + RB[a*8+6], acc[7] + RB[a*8+7]);
        }
    }
}

// ---- thin fill: read er_e coalesced, compute p/q, write 64B record scattered ----
__global__ __launch_bounds__(BS) void fill_kernel(
    const int* __restrict__ srcA, const int* __restrict__ dstA,
    const int* __restrict__ jS, const int* __restrict__ jD,
    const int* __restrict__ offsS, const int* __restrict__ offsD,
    const unsigned short* __restrict__ er_e,   // [E][16] bf16, edge order
    uint4* __restrict__ erec, int E)
{
    int e = blockIdx.x * BS + threadIdx.x;
    if (e >= E) return;
    int s = srcA[e], d = dstA[e];
    int p = offsS[s] + jS[e];
    int q = offsD[d] + jD[e];
    const uint4* ei = (const uint4*)(er_e + (size_t)e * 16);
    uint4 e0 = ei[0];
    uint4 e1 = ei[1];
    uint4* rp = erec + (size_t)p * 4;
    rp[0] = make_uint4((unsigned)s, (unsigned)q, e0.x, e0.y);
    rp[1] = make_uint4(e0.z, e0.w, e1.x, e1.y);
    rp[2] = make_uint4(e1.z, e1.w, 0u, 0u);
    rp[3] = make_uint4(0u, 0u, 0u, 0u);   // complete the 64B line
}

// ---- per-(node, 8-col chunk, k-slot) Y precompute (conv2) ----
template <int IN>
__global__ __launch_bounds__(BS) void ynode_kernel(const float* __restrict__ x,
                                                   const float* __restrict__ W,   // [3][16][IN*8]
                                                   const float* __restrict__ B,   // [3][IN*8]
                                                   const float* __restrict__ RW,  // [3][IN][8]
                                                   const float* __restrict__ RB,  // [3][8]
                                                   unsigned short* __restrict__ Y,
                                                   float* __restrict__ root, int N)
{
    __shared__ float w_lds[IN * 24];
    int t = threadIdx.x;
    int k = blockIdx.y;            // 0..17, block-uniform

    for (int idx = t; idx < IN * 24; idx += BS) {
        int i = idx / 24;
        int j = idx - i * 24;
        int a = j >> 3, o = j & 7;
        float v;
        if (k < 16)       v = W[(((size_t)a * 16 + k) * IN + i) * 8 + o];
        else if (k == 16) v = B[((size_t)a * IN + i) * 8 + o];
        else              v = RW[((size_t)a * IN + i) * 8 + o];
        w_lds[idx] = v;
    }
    __syncthreads();

    int tid = blockIdx.x * BS + t;
    int n = tid / 3;
    int a = tid - n * 3;
    if (n >= N) return;

    float xv[IN];
#pragma unroll
    for (int i = 0; i < IN; i += 4)
        *(float4*)(xv + i) = *(const float4*)(x + (size_t)n * IN + i);

    float acc[8];
#pragma unroll
    for (int o = 0; o < 8; o++) acc[o] = 0.f;
    const float* wb = w_lds + a * 8;
#pragma unroll
    for (int i = 0; i < IN; i++) {
        float xi = xv[i];
#pragma unroll
        for (int o = 0; o < 8; o++)
            acc[o] = fmaf(xi, wb[i * 24 + o], acc[o]);
    }

    if (k < 17) {
        *(uint4*)(Y + ((size_t)k * N + n) * 24 + a * 8) = pack8bf(acc);
    } else {
        float* pr = root + (size_t)n * 24 + a * 8;
        *(float4*)(pr)     = make_float4(acc[0] + RB[a*8+0], acc[1] + RB[a*8+1],
                                         acc[2] + RB[a*8+2], acc[3] + RB[a*8+3]);
        *(float4*)(pr + 4) = make_float4(acc[4] + RB[a*8+4], acc[5] + RB[a*8+5],
                                         acc[6] + RB[a*8+6], acc[7] + RB[a*8+7]);
    }
}

// ---- per-(edge, 8-col part) msg: one 64B record read, k-major 48B-row Y reads ----
__global__ __launch_bounds__(BS) void msg_kernel(
    const uint4* __restrict__ erec,            // [E][4] uint4
    const unsigned short* __restrict__ Y,      // [17][N][24] bf16
    unsigned short* __restrict__ msg16,        // [E][32] bf16, dst-sorted
    int N, int E)
{
    int tid = blockIdx.x * BS + threadIdx.x;
    int p = tid / 3;
    int j = tid - p * 3;
    if (p >= E) return;

    const uint4* rp = erec + (size_t)p * 4;
    uint4 r0 = rp[0];
    uint4 r1 = rp[1];
    uint4 r2 = rp[2];
    unsigned s = r0.x, q = r0.y;

    float er[16];
    unpack2(r0.z, er); unpack2(r0.w, er + 2);
    unpack8(r1, er + 4);
    unpack2(r2.x, er + 12); unpack2(r2.y, er + 14);

    const unsigned short* yb = Y + (size_t)s * 24 + j * 8;
    size_t kstride = (size_t)N * 24;

    float acc[8];
    unpack8(*(const uint4*)(yb + 16 * kstride), acc);   // bias slot
#pragma unroll
    for (int k = 0; k < 16; k++) {
        float t[8];
        unpack8(*(const uint4*)(yb + (size_t)k * kstride), t);
        float ek = er[k];
#pragma unroll
        for (int o = 0; o < 8; o++) acc[o] = fmaf(ek, t[o], acc[o]);
    }
    unsigned short* mrow = msg16 + (size_t)q * 32;
    *(uint4*)(mrow + j * 8) = pack8bf(acc);
    if (j == 0) *(uint4*)(mrow + 24) = make_uint4(0, 0, 0, 0);  // fill line
}

// ---- wave-per-node gather; FUSE_HEAD folds the output head in (conv2) ----
template <bool FUSE_HEAD>
__global__ __launch_bounds__(BS) void gather_kernel(
    const unsigned short* __restrict__ msg16,  // [E][32] bf16, dst-sorted
    const int* __restrict__ offs,
    const int* __restrict__ degi,
    const float* __restrict__ root,            // [N][24] fp32
    float* __restrict__ out,                   // x24 (conv1) or d_out (conv2)
    const float* __restrict__ oW, const float* __restrict__ ob,
    int N)
{
    int n = (blockIdx.x * BS + threadIdx.x) >> 6;   // one wave per node
    if (n >= N) return;
    int lane = threadIdx.x & 63;
    int c = lane & 3;     // uint4-chunk 0..3 (0..2 active)
    int r = lane >> 2;    // row within 16-row tile

    int off = offs[n];
    int d = degi[n];

    float s[8], m[8];
#pragma unroll
    for (int o = 0; o < 8; o++) { s[o] = 0.f; m[o] = -3.402823466e38f; }

    if (c < 3) {
        const unsigned short* base = msg16 + (size_t)off * 32 + c * 8;
        for (int j = r; j < d; j += 16) {
            uint4 v = *(const uint4*)(base + (size_t)j * 32);
            float t[8];
            unpack8(v, t);
#pragma unroll
            for (int o = 0; o < 8; o++) {
                s[o] += t[o];
                m[o] = fmaxf(m[o], t[o]);
            }
        }
    }
#pragma unroll
    for (int mask = 4; mask < 64; mask <<= 1) {
#pragma unroll
        for (int o = 0; o < 8; o++) {
            s[o] += __shfl_xor(s[o], mask);
            m[o] = fmaxf(m[o], __shfl_xor(m[o], mask));
        }
    }

    bool active = (lane < 3);
    float rr[8];
    if (active) {
        float inv = 1.f / fmaxf((float)d, 1.f);
        const float* pr = root + (size_t)n * 24 + lane * 8;
        float4 r0 = *(const float4*)(pr);
        float4 r1 = *(const float4*)(pr + 4);
        float rb[8] = {r0.x, r0.y, r0.z, r0.w, r1.x, r1.y, r1.z, r1.w};
#pragma unroll
        for (int o = 0; o < 8; o++) {
            float agg = (lane == 0) ? s[o] * inv
                      : (lane == 1) ? ((d > 0) ? m[o] : 0.f)
                      : s[o];
            rr[o] = fmaxf(rb[o] + agg, 0.f);
        }
    }

    if (!FUSE_HEAD) {
        if (active) {
            float* po = out + (size_t)n * 24 + lane * 8;
            *(float4*)(po)     = make_float4(rr[0], rr[1], rr[2], rr[3]);
            *(float4*)(po + 4) = make_float4(rr[4], rr[5], rr[6], rr[7]);
        }
    } else {
        float l0p = 0.f, l1p = 0.f;
        if (active) {
#pragma unroll
            for (int o = 0; o < 8; o++) {
                l0p = fmaf(rr[o], oW[(lane * 8 + o) * 2 + 0], l0p);
                l1p = fmaf(rr[o], oW[(lane * 8 + o) * 2 + 1], l1p);
            }
        }
        float l0 = __shfl(l0p, 0) + __shfl(l0p, 1) + __shfl(l0p, 2);
        float l1 = __shfl(l1p, 0) + __shfl(l1p, 1) + __shfl(l1p, 2);
        if (lane == 0) {
            l0 += ob[0]; l1 += ob[1];
            out[2 * (size_t)n + 0] = l0;
            out[2 * (size_t)n + 1] = l1;
            float mx = fmaxf(l0, l1);
            float e0 = __expf(l0 - mx), e1 = __expf(l1 - mx);
            float sm = e0 + e1;
            out[2 * (size_t)N + 2 * (size_t)n + 0] = e0 / sm;
            out[2 * (size_t)N + 2 * (size_t)n + 1] = e1 / sm;
        }
    }
}

extern "C" void kernel_launch(void* const* d_in, const int* in_sizes, int n_in,
                              void* d_out, int out_size, void* d_ws, size_t ws_size,
                              hipStream_t stream)
{
    const float* x_feat = (const float*)d_in[0];
    const int*   eidx   = (const int*)d_in[1];
    const float* eattr  = (const float*)d_in[2];
    const float* lpW = (const float*)d_in[3];
    const float* lpb = (const float*)d_in[4];
    const float* tW  = (const float*)d_in[5];
    const float* tb  = (const float*)d_in[6];
    const float* eW1 = (const float*)d_in[7];
    const float* eb1 = (const float*)d_in[8];
    const float* eW2 = (const float*)d_in[9];
    const float* eb2 = (const float*)d_in[10];
    const float* c1W = (const float*)d_in[11];
    const float* c1B = (const float*)d_in[12];
    const float* c1R = (const float*)d_in[13];
    const float* c1b = (const float*)d_in[14];
    const float* c2W = (const float*)d_in[15];
    const float* c2B = (const float*)d_in[16];
    const float* c2R = (const float*)d_in[17];
    const float* c2b = (const float*)d_in[18];
    const float* oW  = (const float*)d_in[19];
    const float* ob  = (const float*)d_in[20];

    int N = in_sizes[0] / 24;
    int E = in_sizes[1] / 2;
    const int* srcA = eidx;
    const int* dstA = eidx + E;

    char* wsb = (char*)d_ws;
    size_t off = 0;
    auto alloc = [&](size_t bytes) {
        off = (off + 255) & ~(size_t)255;
        void* p = wsb + off;
        off += bytes;
        return p;
    };
    unsigned short* Y     = (unsigned short*)alloc((size_t)17 * N * 24 * 2);
    unsigned short* msg16 = (unsigned short*)alloc((size_t)E * 32 * 2);
    uint4* erec = (uint4*)alloc((size_t)E * 64);
    unsigned short* er_e  = (unsigned short*)alloc((size_t)E * 16 * 2);
    float* root = (float*)alloc((size_t)N * 24 * 4);
    float* x16  = (float*)alloc((size_t)N * 16 * 4);
    float* x24a = (float*)alloc((size_t)N * 24 * 4);
    int* ibase  = (int*)alloc(((size_t)2 * N + 2) * 4);  // cntS | cntD | cursS | cursD (zeroed)
    int* cntS = ibase;
    int* cntD = ibase + N;
    int* cursS = ibase + 2 * N;
    int* cursD = ibase + 2 * N + 1;
    int* offsS = (int*)alloc((size_t)N * 4);
    int* offsD = (int*)alloc((size_t)N * 4);
    int* jS    = (int*)alloc((size_t)E * 4);
    int* jD    = (int*)alloc((size_t)E * 4);

    dim3 blk(BS);
    int nb_nodes = (N + BS - 1) / BS;
    int nb_edges = (E + BS - 1) / BS;
    int nb_msg   = (3 * E + BS - 1) / BS;
    int nb_gath  = ((size_t)N * 64 + BS - 1) / BS;     // one wave per node
    int nb_y3    = (3 * N + BS - 1) / BS;              // thread = (node, chunk)
    int nbY      = nb_y3 * 18;                         // ynode16 flattened block count
    dim3 ygrid(nb_y3, 18);

    hipMemsetAsync(ibase, 0, (2 * (size_t)N + 2) * 4, stream);

    // prep (196 tiny blocks first) + per-thread fused histogram/trunk
    prep_combo_kernel<<<nb_nodes + nb_edges, blk, 0, stream>>>(
        x_feat, lpW, lpb, tW, tb, x16, srcA, dstA, cntS, cntD, jS, jD,
        eattr, eW1, eb1, eW2, eb2, er_e, N, E, nb_nodes);

    // fused offsets (tiny) + ynode16 (depends only on x16)
    offs_ynode16_kernel<<<nb_nodes + nbY, blk, 0, stream>>>(
        cntS, cntD, offsS, offsD, cursS, cursD,
        x16, c1W, c1B, c1R, c1b, Y, root, N, nb_nodes, nb_y3);

    // thin fill: scatter er_e into src-sorted 64B records
    fill_kernel<<<nb_edges, blk, 0, stream>>>(srcA, dstA, jS, jD, offsS, offsD,
                                              er_e, erec, E);

    // ---- conv1 ----
    msg_kernel<<<nb_msg, blk, 0, stream>>>(erec, Y, msg16, N, E);
    gather_kernel<false><<<nb_gath, blk, 0, stream>>>(msg16, offsD, cntD, root, x24a,
                                                      oW, ob, N);

    // ---- conv2 (head fused into gather) ----
    ynode_kernel<24><<<ygrid, blk, 0, stream>>>(x24a, c2W, c2B, c2R, c2b, Y, root, N);
    msg_kernel<<<nb_msg, blk, 0, stream>>>(erec, Y, msg16, N, E);
    gather_kernel<true><<<nb_gath, blk, 0, stream>>>(msg16, offsD, cntD, root,
                                                     (float*)d_out, oW, ob, N);
}